// Round 6
// baseline (325.589 us; speedup 1.0000x reference)
//
#include <hip/hip_runtime.h>

#define B_   16
#define TXT  32
#define VID  2048
#define D_   256
#define S_   2080
#define SP   2176   // padded sequence rows for Q
#define NKT  34     // kv tiles (64 each) in K/V layouts
#define GTOT 17424  // 16 b * 33 qt * 33 kv global iterations

typedef unsigned short ushort_t;
typedef __attribute__((ext_vector_type(8))) short short8;
typedef __attribute__((ext_vector_type(4))) short short4v;
typedef __attribute__((ext_vector_type(4))) float f32x4;
typedef __attribute__((ext_vector_type(16))) float f32x16;

__device__ __forceinline__ ushort_t f2bf(float f) {
  unsigned u = __builtin_bit_cast(unsigned, f);
  unsigned r = (u + 0x7FFFu + ((u >> 16) & 1u)) >> 16;   // RNE (finite values)
  return (ushort_t)r;
}
__device__ __forceinline__ float bf2f(ushort_t h) {
  unsigned u = ((unsigned)h) << 16;
  return __builtin_bit_cast(float, u);
}

__device__ __forceinline__ void g2l16(void* lds, const void* g) {
  __builtin_amdgcn_global_load_lds(
      (const __attribute__((address_space(1))) char*)g,
      (__attribute__((address_space(3))) char*)lds, 16, 0, 0);
}

__device__ __forceinline__ f32x4 mfma16(short8 a, short8 b, f32x4 c) {
  return __builtin_amdgcn_mfma_f32_16x16x32_bf16(a, b, c, 0, 0, 0);
}
__device__ __forceinline__ f32x16 mfma32(short8 a, short8 b, f32x16 c) {
  return __builtin_amdgcn_mfma_f32_32x32x16_bf16(a, b, c, 0, 0, 0);
}

// K layout (per batch, per 64-kv tile, 32KB): [kstep16][64 kv][16 us], ushort idx ^ ((kv>>2)&1)<<3
// V layout (per batch, per 64-kv tile, 32KB): [kvstep4][256 d][16 us], ushort idx ^ ((d>>2)&1)<<3
// (XOR spreads the 32B row stride across bank groups -> conflict-free b128 reads)
// tile base (ushorts): (b*NKT + ktile) << 14

// ---------------- xpos table ----------------
__global__ void tbl_kernel(float* __restrict__ tbl) {
  int idx = blockIdx.x * 256 + threadIdx.x;     // 2048*128 = 262144
  int n = idx >> 7, i = idx & 127;
  float invf = powf(10000.0f, -(float)i / 128.0f);
  float ang = (float)n * invf;
  float s, co;
  sincosf(ang, &s, &co);
  float sv = ((float)(2 * i) + 102.4f) / 358.4f;
  float sc = powf(sv, (float)n / 512.0f);
  float4 r;
  r.x = co * sc; r.y = s * sc; r.z = co / sc; r.w = s / sc;
  *(float4*)(tbl + (size_t)idx * 4) = r;
}

// ---------------- sigmoid mask (row-major bf16) + sparsity loss ----------------
__global__ void sig_loss_kernel(const float* __restrict__ learn, ushort_t* __restrict__ sigp,
                                float* __restrict__ loss) {
  const int tid = threadIdx.x;
  const int base = (blockIdx.x * 256 + tid) * 8;
  float4 v0 = *(const float4*)(learn + base);
  float4 v1 = *(const float4*)(learn + base + 4);
  float vals[8] = {v0.x, v0.y, v0.z, v0.w, v1.x, v1.y, v1.z, v1.w};
  float acc = 0.f;
  short8 sh;
  #pragma unroll
  for (int j = 0; j < 8; ++j) {
    int idx = base + j;
    float s = 1.0f / (1.0f + expf(-vals[j]));
    sh[j] = (short)f2bf(s);
    int rr = idx >> 11, cc = idx & 2047;
    if (rr != cc) acc += s;
  }
  *(short8*)(sigp + base) = sh;
  __shared__ float red[256];
  red[tid] = acc;
  __syncthreads();
  #pragma unroll
  for (int st = 128; st > 0; st >>= 1) {
    if (tid < st) red[tid] += red[tid + st];
    __syncthreads();
  }
  if (tid == 0) atomicAdd(loss, red[0] * (1.0f / 4194304.0f));
}

// ---------------- zero-fill padding regions ----------------
__global__ void pad0_kernel(ushort_t* __restrict__ Qp, ushort_t* __restrict__ Ks,
                            ushort_t* __restrict__ VTs) {
  int i = blockIdx.x * 256 + threadIdx.x;      // 81920 total, each writes 8 ushorts
  short8 z = {0, 0, 0, 0, 0, 0, 0, 0};
  if (i < 49152) {                             // Qp rows 2080..2175, 16 batches
    int bb = i / 3072, rem = i - bb * 3072;
    int row = 2080 + (rem >> 5), c8 = (rem & 31) * 8;
    *(short8*)(Qp + ((size_t)bb * SP + row) * D_ + c8) = z;
  } else if (i < 65536) {                      // Ks tile 32, kv rows 32..63
    int j = i - 49152; int bb = j >> 10; int rem = j & 1023;
    int kstep = rem >> 6, ch = rem & 63;
    size_t base = ((size_t)(bb * NKT + 32)) << 14;
    *(short8*)(Ks + base + kstep * 1024 + 512 + ch * 8) = z;
  } else if (i < 81920) {                      // VTs tile 32, kvsteps 2..3
    int j = i - 65536; int bb = j >> 10; int rem = j & 1023;
    size_t base = (((size_t)(bb * NKT + 32)) << 14) + 8192;
    *(short8*)(VTs + base + rem * 8) = z;
  }
}

// ---------------- weight transpose ----------------
__global__ void wt_kernel(const float* __restrict__ Wq, const float* __restrict__ Wk,
                          const float* __restrict__ Wv, ushort_t* __restrict__ WT) {
  __shared__ float t[64][68];
  const int k0 = blockIdx.x * 64, n0 = blockIdx.y * 64, mt = blockIdx.z;
  const float* W = (mt == 0) ? Wq : (mt == 1) ? Wk : Wv;
  int tid = threadIdx.x;
  int r = tid >> 4, cq = (tid & 15) * 4;
  #pragma unroll
  for (int m = 0; m < 4; ++m) {
    int k = m * 16 + r;
    float4 v = *(const float4*)(W + (size_t)(k0 + k) * 256 + n0 + cq);
    t[k][cq] = v.x; t[k][cq + 1] = v.y; t[k][cq + 2] = v.z; t[k][cq + 3] = v.w;
  }
  __syncthreads();
  #pragma unroll
  for (int m = 0; m < 4; ++m) {
    int n = m * 16 + r;
    short4v h;
    h[0] = (short)f2bf(t[cq + 0][n]);
    h[1] = (short)f2bf(t[cq + 1][n]);
    h[2] = (short)f2bf(t[cq + 2][n]);
    h[3] = (short)f2bf(t[cq + 3][n]);
    *(short4v*)(WT + ((size_t)mt * D_ + n0 + n) * D_ + k0 + cq) = h;
  }
}

// ---------------- txt rows ----------------
__global__ void txt_kernel(const float* __restrict__ src,
                           const float* __restrict__ Wq, const float* __restrict__ Wk,
                           const float* __restrict__ Wv,
                           ushort_t* __restrict__ Qp, ushort_t* __restrict__ Ks,
                           ushort_t* __restrict__ VTs) {
  __shared__ float a_s[8][256];
  __shared__ float x_s[8][256];
  const int tg = blockIdx.x;
  const int b  = blockIdx.y;
  const int c  = threadIdx.x;
  #pragma unroll
  for (int t = 0; t < 8; ++t) {
    int row = tg * 8 + t;
    float x = src[((size_t)b * S_ + row) * D_ + c];
    float xe = (float)(row + 1) * (6.283185307179586f / (32.0f + 1e-6f));
    int i = c >> 1;
    float dimt = powf(10000.0f, (2.0f * (float)i) / 256.0f);
    float ang = xe / dimt;
    float pv = (c & 1) ? cosf(ang) : sinf(ang);
    x_s[t][c] = x;
    a_s[t][c] = x + pv;
  }
  __syncthreads();
  float q[8] = {0,0,0,0,0,0,0,0}, k[8] = {0,0,0,0,0,0,0,0}, v[8] = {0,0,0,0,0,0,0,0};
  for (int kk = 0; kk < 256; ++kk) {
    float wq = Wq[(size_t)kk * 256 + c];
    float wk = Wk[(size_t)kk * 256 + c];
    float wv = Wv[(size_t)kk * 256 + c];
    #pragma unroll
    for (int t = 0; t < 8; ++t) {
      q[t] = fmaf(a_s[t][kk], wq, q[t]);
      k[t] = fmaf(a_s[t][kk], wk, k[t]);
      v[t] = fmaf(x_s[t][kk], wv, v[t]);
    }
  }
  #pragma unroll
  for (int t = 0; t < 8; ++t) {
    int row = tg * 8 + t;          // kv row (txt rows are kv 0..31, ktile 0)
    Qp[((size_t)b * SP + row) * D_ + c] = f2bf(q[t]);
    size_t kidx = ((((size_t)(b * NKT)) << 14) + (c >> 4) * 1024 + row * 16 + (c & 15)) ^ (((row >> 2) & 1) << 3);
    Ks[kidx] = f2bf(k[t]);
    size_t vidx = ((((size_t)(b * NKT)) << 14) + (row >> 4) * 4096 + c * 16 + (row & 15)) ^ (((c >> 2) & 1) << 3);
    VTs[vidx] = f2bf(v[t]);
  }
}

// ---------------- vid projection GEMM (+xpos epilogue, swizzled K/V out) ----------------
__global__ __launch_bounds__(256, 2) void vid_gemm(
    const float* __restrict__ src, const ushort_t* __restrict__ WT,
    const float* __restrict__ tbl,
    ushort_t* __restrict__ Qp, ushort_t* __restrict__ Ks, ushort_t* __restrict__ VTs) {
  __shared__ __align__(16) ushort_t ldsA[64 * 64];
  __shared__ __align__(16) ushort_t ldsB[64 * 64];

  const int rt = blockIdx.x;
  const int b  = blockIdx.y;
  const int ct = blockIdx.z;
  const int nt = ct >> 2;
  const int n0 = (ct & 3) * 64;
  const int tid = threadIdx.x;
  const int wv = tid >> 6, lane = tid & 63, l15 = lane & 15, l4 = lane >> 4;

  f32x4 acc[4];
  #pragma unroll
  for (int t2 = 0; t2 < 4; ++t2) { acc[t2][0] = 0.f; acc[t2][1] = 0.f; acc[t2][2] = 0.f; acc[t2][3] = 0.f; }

  for (int kk = 0; kk < 256; kk += 64) {
    #pragma unroll
    for (int m = 0; m < 4; ++m) {
      int q = m * 256 + tid;
      int r = q >> 4;
      int kc = (q & 15) * 4;
      const float4 v = *(const float4*)(src + ((size_t)b * S_ + TXT + rt * 64 + r) * D_ + kk + kc);
      short4v h;
      h[0] = (short)f2bf(v.x); h[1] = (short)f2bf(v.y);
      h[2] = (short)f2bf(v.z); h[3] = (short)f2bf(v.w);
      int off = ((r << 7) + (kc << 1)) ^ ((r & 7) << 4);
      *(short4v*)((char*)ldsA + off) = h;
    }
    #pragma unroll
    for (int m = 0; m < 2; ++m) {
      int p = (m * 256 + tid) * 16;
      int nl = p >> 7;
      int c = (p & 127) ^ ((nl & 7) << 4);
      g2l16((char*)ldsB + p, (const char*)(WT + ((size_t)nt * D_ + n0 + nl) * D_ + kk) + c);
    }
    __syncthreads();
    #pragma unroll
    for (int ks = 0; ks < 2; ++ks) {
      int ar = wv * 16 + l15;
      int aoff = ((ar << 7) + ((ks * 32 + l4 * 8) << 1)) ^ ((ar & 7) << 4);
      short8 av = *(const short8*)((const char*)ldsA + aoff);
      #pragma unroll
      for (int t2 = 0; t2 < 4; ++t2) {
        int nl = t2 * 16 + l15;
        int boff = ((nl << 7) + ((ks * 32 + l4 * 8) << 1)) ^ ((nl & 7) << 4);
        short8 bv = *(const short8*)((const char*)ldsB + boff);
        acc[t2] = mfma16(av, bv, acc[t2]);
      }
    }
    __syncthreads();
  }

  const int rowl = wv * 16 + l4 * 4;
  if (nt < 2) {
    #pragma unroll
    for (int t2 = 0; t2 < 4; ++t2) {
      int c = n0 + t2 * 16 + l15;
      #pragma unroll
      for (int r = 0; r < 4; ++r) {
        int n = rt * 64 + rowl + r;
        float x = acc[t2][r];
        float xp = __shfl_xor(x, 1);
        const float4 tb = *(const float4*)(tbl + ((size_t)n * 128 + (c >> 1)) * 4);
        float cs = (nt == 0) ? tb.x : tb.z;
        float ss = (nt == 0) ? tb.y : tb.w;
        float val = (c & 1) ? fmaf(x, cs, xp * ss) : fmaf(x, cs, -xp * ss);
        if (nt == 0) {
          Qp[((size_t)b * SP + TXT + n) * D_ + c] = f2bf(val);
        } else {
          int kvg = TXT + n;
          size_t kidx = ((((size_t)(b * NKT + (kvg >> 6))) << 14) + (c >> 4) * 1024 + (kvg & 63) * 16 + (c & 15))
                        ^ (((kvg >> 2) & 1) << 3);
          Ks[kidx] = f2bf(val);
        }
      }
    }
  } else {
    #pragma unroll
    for (int t2 = 0; t2 < 4; ++t2)
      #pragma unroll
      for (int r = 0; r < 4; ++r) {
        int rr = rowl + r;
        int cc = t2 * 16 + l15;
        int off = ((rr << 7) + (cc << 1)) ^ ((rr & 7) << 4);
        *(ushort_t*)((char*)ldsA + off) = f2bf(acc[t2][r]);
      }
    __syncthreads();
    int n = tid >> 2;                 // local d 0..63
    int rc = (tid & 3) * 16;          // local vid row chunk
    short8 o0, o1;
    #pragma unroll
    for (int j = 0; j < 8; ++j) {
      int rr = rc + j;
      int off = ((rr << 7) + (n << 1)) ^ ((rr & 7) << 4);
      o0[j] = *(const short*)((const char*)ldsA + off);
    }
    #pragma unroll
    for (int j = 0; j < 8; ++j) {
      int rr = rc + 8 + j;
      int off = ((rr << 7) + (n << 1)) ^ ((rr & 7) << 4);
      o1[j] = *(const short*)((const char*)ldsA + off);
    }
    int d = n0 + n;
    int kvg0 = TXT + rt * 64 + rc;    // 16-aligned
    size_t base = (((size_t)(b * NKT + (kvg0 >> 6))) << 14) + ((kvg0 >> 4) & 3) * 4096 + d * 16;
    int swz8 = ((d >> 2) & 1) << 3;
    *(short8*)(VTs + base + swz8) = o0;
    *(short8*)(VTs + base + (swz8 ^ 8)) = o1;
  }
}

// ---------------- fused masked attention v6: producer/consumer waves ----------------
// 512 thr, 1 block/CU, grid 256 (no tail). Waves 0-3: QK(i)+mask+pack->Pb[i&1].
// Waves 4-7: PV(i-1) from Pb/Vb[(i-1)&1]. K,V,P double-buffered (144KB LDS).
// Depth-2 staging with counted vmcnt (QK batch=12, PV batch=8); 2 barriers/phase.
__global__ __launch_bounds__(512, 1) void attn_kernel(
    const ushort_t* __restrict__ Qp, const ushort_t* __restrict__ Ks,
    const ushort_t* __restrict__ VTs, const ushort_t* __restrict__ sigp,
    float* __restrict__ out) {
  __shared__ __align__(16) ushort_t Kb[2][16384];
  __shared__ __align__(16) ushort_t Vb[2][16384];
  __shared__ __align__(16) ushort_t Pb[2][4096];

  const int kblk = blockIdx.x;                      // 0..255
  const int bs = (kblk & 7) * 32 + (kblk >> 3);     // XCD-chunked bijective swizzle
  const int gs = bs * 68 + (bs < 16 ? bs : 16);
  const int ge = gs + 68 + (bs < 16 ? 1 : 0);       // block covers [gs, ge)

  const int tid = threadIdx.x;
  const int wid = tid >> 6, lane = tid & 63;
  const int l31 = lane & 31, l5 = lane >> 5;
  const bool isQK = wid < 4;
  const int qh = (wid >> 1) & 1, kh = wid & 1;
  const int d0 = (wid & 3) * 64;                    // PV wave d-slice

  // g -> (b, qt, kvt)
  int cb_b = gs / 1089;
  int rrem = gs - cb_b * 1089;
  int cb_q = rrem / 33;
  int cb_k = rrem - cb_q * 33;

  auto stage = [&](ushort_t* dst, const ushort_t* srcb, int bb, int tt) {
    const char* src = (const char*)srcb + (((size_t)(bb * NKT + tt)) << 15);
    #pragma unroll
    for (int m = 0; m < 4; ++m) { int s = m * 512 + tid; g2l16((char*)dst + s * 16, src + s * 16); }
  };

  short8 qf[16];
  int4 mq[4];
  const int qloc = qh * 32 + l31;

  auto ldq = [&](int bb, int qq) {
    const ushort_t* qrow = Qp + ((size_t)bb * SP + qq * 64 + qloc) * D_ + l5 * 8;
    #pragma unroll
    for (int ks = 0; ks < 16; ++ks) qf[ks] = *(const short8*)(qrow + ks * 16);
  };
  auto ldmask = [&](int qq, int tt) {
    int q = qq * 64 + qloc;
    int qc = q - TXT; qc = qc < 0 ? 0 : (qc > 2047 ? 2047 : qc);
    int kvp = tt * 64 + kh * 32 - TXT;
    int kvc = (kvp >= 0 && kvp <= 2016) ? kvp : 0;
    const int4* mrow = (const int4*)(sigp + (size_t)qc * 2048 + kvc);
    mq[0] = mrow[0]; mq[1] = mrow[1]; mq[2] = mrow[2]; mq[3] = mrow[3];
  };

  f32x16 oacc[2][2];
  #pragma unroll
  for (int i2 = 0; i2 < 2; ++i2)
    #pragma unroll
    for (int j2 = 0; j2 < 2; ++j2)
      #pragma unroll
      for (int r = 0; r < 16; ++r) oacc[i2][j2][r] = 0.f;

  const int kswz = ((l31 >> 2) & 1) << 4;
  const int pswz = (l31 & 7) << 4;

  // ---- prologue: K(gs); batch(gs-1) = {mask(gs), K(gs+1), V(gs)} ----
  int n1_b = cb_b, n1_q = cb_q, n1_k = cb_k;
  if (gs <= ge - 2) { ++n1_k; if (n1_k == 33) { n1_k = 0; ++n1_q; if (n1_q == 33) { n1_q = 0; ++n1_b; } } }
  stage(Kb[gs & 1], Ks, cb_b, cb_k);
  if (isQK) ldmask(cb_q, cb_k);
  stage(Kb[(gs + 1) & 1], Ks, n1_b, n1_k);
  stage(Vb[gs & 1], VTs, cb_b, cb_k);
  if (isQK) { asm volatile("s_waitcnt vmcnt(12)" ::: "memory"); }
  else      { asm volatile("s_waitcnt vmcnt(8)"  ::: "memory"); }
  __builtin_amdgcn_sched_barrier(0);
  __builtin_amdgcn_s_barrier();
  __builtin_amdgcn_sched_barrier(0);

  int pv_b = cb_b, pv_q = cb_q, pv_k = cb_k;   // triple of g = i-1 (valid for i > gs)

  for (int i = gs; i <= ge; ++i) {
    const int cb = i & 1;
    // n1 = decode(min(i+1, ge-1)), n2 = decode(min(i+2, ge-1))
    n1_b = cb_b; n1_q = cb_q; n1_k = cb_k;
    if (i <= ge - 2) { ++n1_k; if (n1_k == 33) { n1_k = 0; ++n1_q; if (n1_q == 33) { n1_q = 0; ++n1_b; } } }
    int n2_b = n1_b, n2_q = n1_q, n2_k = n1_k;
    if (i <= ge - 3) { ++n2_k; if (n2_k == 33) { n2_k = 0; ++n2_q; if (n2_q == 33) { n2_q = 0; ++n2_b; } } }

    if (isQK) {
      if (i < ge) {
        if (cb_k == 0 || i == gs) ldq(cb_b, cb_q);
        f32x16 s0, s1;
        #pragma unroll
        for (int r = 0; r < 16; ++r) { s0[r] = 0.f; s1[r] = 0.f; }
        const int krow = (kh * 32 + l31) * 32 + l5 * 16;
        __builtin_amdgcn_s_setprio(1);
        #pragma unroll
        for (int ks = 0; ks < 8; ++ks) {
          short8 ka = *(const short8*)((const char*)Kb[cb] + ((ks * 2048 + krow) ^ kswz));
          short8 kc = *(const short8*)((const char*)Kb[cb] + (((ks + 8) * 2048 + krow) ^ kswz));
          s0 = mfma32(ka, qf[ks], s0);
          s1 = mfma32(kc, qf[ks + 8], s1);
        }
        __builtin_amdgcn_s_setprio(0);
        // mask + pack P (bf16) -> Pb[cb]
        {
          int q = cb_q * 64 + qloc;
          bool qv = (q >= TXT) && (q < S_);
          int kvp = cb_k * 64 + kh * 32 - TXT;
          bool kvv = (kvp >= 0 && kvp <= 2016);
          bool ok = qv && kvv;
          const unsigned* mw = (const unsigned*)mq;
          #pragma unroll
          for (int t = 0; t < 4; ++t) {
            unsigned w0p, w1p;
            {
              unsigned wa = mw[4 * t + 0], wb = mw[4 * t + 2];
              unsigned w = l5 ? wb : wa;
              float m0 = ok ? bf2f((ushort_t)(w & 0xFFFFu)) : 1.0f;
              float m1 = ok ? bf2f((ushort_t)(w >> 16)) : 1.0f;
              int r = 4 * t;
              float p0 = (s0[r] + s1[r]) * m0;
              float p1 = (s0[r + 1] + s1[r + 1]) * m1;
              asm("v_cvt_pk_bf16_f32 %0, %1, %2" : "=v"(w0p) : "v"(p0), "v"(p1));
            }
            {
              unsigned wa = mw[4 * t + 1], wb = mw[4 * t + 3];
              unsigned w = l5 ? wb : wa;
              float m0 = ok ? bf2f((ushort_t)(w & 0xFFFFu)) : 1.0f;
              float m1 = ok ? bf2f((ushort_t)(w >> 16)) : 1.0f;
              int r = 4 * t + 2;
              float p0 = (s0[r] + s1[r]) * m0;
              float p1 = (s0[r + 1] + s1[r + 1]) * m1;
              asm("v_cvt_pk_bf16_f32 %0, %1, %2" : "=v"(w1p) : "v"(p0), "v"(p1));
            }
            int off = ((qloc << 7) + (kh << 6) + (t << 4) + (l5 << 3)) ^ pswz;
            *(uint2*)((char*)Pb[cb] + off) = make_uint2(w0p, w1p);
          }
        }
        asm volatile("s_waitcnt lgkmcnt(0)" ::: "memory");
        __builtin_amdgcn_sched_barrier(0);
      }
    } else {
      if (i > gs) {
        const int pbuf = cb ^ 1;
        __builtin_amdgcn_s_setprio(1);
        #pragma unroll
        for (int ks = 0; ks < 4; ++ks) {
          short8 pf0 = *(const short8*)((const char*)Pb[pbuf] + ((l31 * 128 + ks * 32 + l5 * 16) ^ pswz));
          short8 pf1 = *(const short8*)((const char*)Pb[pbuf] + (((32 + l31) * 128 + ks * 32 + l5 * 16) ^ pswz));
          short8 vf0 = *(const short8*)((const char*)Vb[pbuf] + ((ks * 8192 + (d0 + l31) * 32 + l5 * 16) ^ kswz));
          short8 vf1 = *(const short8*)((const char*)Vb[pbuf] + ((ks * 8192 + (d0 + 32 + l31) * 32 + l5 * 16) ^ kswz));
          oacc[0][0] = mfma32(pf0, vf0, oacc[0][0]);
          oacc[0][1] = mfma32(pf0, vf1, oacc[0][1]);
          oacc[1][0] = mfma32(pf1, vf0, oacc[1][0]);
          oacc[1][1] = mfma32(pf1, vf1, oacc[1][1]);
        }
        __builtin_amdgcn_s_setprio(0);
        if (pv_k == 32 || i == ge) {          // row finished (or block end): flush partials
          #pragma unroll
          for (int qg2 = 0; qg2 < 2; ++qg2)
            #pragma unroll
            for (int dg = 0; dg < 2; ++dg)
              #pragma unroll
              for (int r = 0; r < 16; ++r) {
                int qg = pv_q * 64 + qg2 * 32 + (r & 3) + 8 * (r >> 2) + 4 * l5;
                int dd = d0 + dg * 32 + l31;
                if (qg < S_)
                  unsafeAtomicAdd(&out[((size_t)pv_b * S_ + qg) * D_ + dd], oacc[qg2][dg][r]);
                oacc[qg2][dg][r] = 0.f;
              }
        }
      }
    }

    __builtin_amdgcn_sched_barrier(0);
    __builtin_amdgcn_s_barrier();             // barrier A: phase reads/writes done
    __builtin_amdgcn_sched_barrier(0);

    if (i < ge) {
      if (isQK) ldmask(n1_q, n1_k);           // mask(i+1): 4 loads (oldest of batch)
      stage(Kb[cb], Ks, n2_b, n2_k);          // K(i+2)
      stage(Vb[cb ^ 1], VTs, n1_b, n1_k);     // V(i+1)
      __builtin_amdgcn_sched_barrier(0);
      if (isQK) { asm volatile("s_waitcnt vmcnt(12)" ::: "memory"); }
      else      { asm volatile("s_waitcnt vmcnt(8)"  ::: "memory"); }
      __builtin_amdgcn_sched_barrier(0);
    }
    __builtin_amdgcn_s_barrier();             // barrier B: K(i+1)/V(i) visible block-wide
    __builtin_amdgcn_sched_barrier(0);

    pv_b = cb_b; pv_q = cb_q; pv_k = cb_k;
    cb_b = n1_b; cb_q = n1_q; cb_k = n1_k;
  }
}

extern "C" void kernel_launch(void* const* d_in, const int* in_sizes, int n_in,
                              void* d_out, int out_size, void* d_ws, size_t ws_size,
                              hipStream_t stream) {
  (void)in_sizes; (void)n_in; (void)ws_size;
  const float* src   = (const float*)d_in[0];
  const float* learn = (const float*)d_in[1];
  const float* Wtq = (const float*)d_in[2];
  const float* Wtk = (const float*)d_in[3];
  const float* Wtv = (const float*)d_in[4];
  const float* Wvq = (const float*)d_in[5];
  const float* Wvk = (const float*)d_in[6];
  const float* Wvv = (const float*)d_in[7];
  float* out = (float*)d_out;

  char* ws = (char*)d_ws;
  const size_t QKV_ONE = (size_t)B_ * SP * D_ * 2;
  const size_t QP_OFF  = 0;
  const size_t KS_OFF  = QP_OFF + QKV_ONE;
  const size_t VT_OFF  = KS_OFF + QKV_ONE;
  const size_t SIG_OFF = VT_OFF + QKV_ONE;
  const size_t TBL_OFF = SIG_OFF + (size_t)VID * VID * 2;
  const size_t WT_OFF  = TBL_OFF + (size_t)VID * 128 * 4 * sizeof(float);

  ushort_t* Qp   = (ushort_t*)(ws + QP_OFF);
  ushort_t* Ks   = (ushort_t*)(ws + KS_OFF);
  ushort_t* VTs  = (ushort_t*)(ws + VT_OFF);
  ushort_t* sigp = (ushort_t*)(ws + SIG_OFF);
  float*    tbl  = (float*)(ws + TBL_OFF);
  ushort_t* WT   = (ushort_t*)(ws + WT_OFF);

  hipMemsetAsync(d_out, 0, (size_t)out_size * sizeof(float), stream);  // atomic partials + loss
  pad0_kernel<<<320, 256, 0, stream>>>(Qp, Ks, VTs);
  tbl_kernel<<<1024, 256, 0, stream>>>(tbl);
  sig_loss_kernel<<<2048, 256, 0, stream>>>(learn, sigp, out + (size_t)B_ * S_ * D_);
  wt_kernel<<<dim3(4, 4, 3), 256, 0, stream>>>(Wvq, Wvk, Wvv, WT);
  txt_kernel<<<dim3(4, B_), 256, 0, stream>>>(src, Wtq, Wtk, Wtv, Qp, Ks, VTs);
  vid_gemm<<<dim3(32, B_, 12), 256, 0, stream>>>(src, WT, tbl, Qp, Ks, VTs);
  attn_kernel<<<dim3(256), 512, 0, stream>>>(Qp, Ks, VTs, sigp, out);
}